// Round 4
// baseline (440.966 us; speedup 1.0000x reference)
//
#include <hip/hip_runtime.h>
#include <hip/hip_bf16.h>

typedef unsigned short u16;
typedef __attribute__((ext_vector_type(8))) short bf16x8;  // 8 bf16 = 4 VGPRs
typedef __attribute__((ext_vector_type(4))) float f32x4;

#define NH   32
#define HD   128
#define SEQ  2048
#define BQ   64
#define BK   64

// smem (u16 units): Ks [0,8192) Vt [8192,16384) Ps [16384,20480)  = 40960 B
// pass A overlays KsA (128x128) on [0,16384)
#define VT_OFF 8192
#define PS_OFF 16384

// Vt swizzle key: phys group p = g ^ vt_key(d) within a d-row of 8 groups
__device__ __forceinline__ int vt_key(int d) { return (d & 7) ^ ((d >> 3) & 7); }

__device__ __forceinline__ u16 f2b(float x) {
  __hip_bfloat16 hb = __float2bfloat16(x);
  return *(u16*)&hb;
}

// load 8 fp32 (32B), convert to bf16x8
__device__ __forceinline__ bf16x8 cvt8(const float* src) {
  float4 a = *(const float4*)(src);
  float4 b = *(const float4*)(src + 4);
  u16 t[8];
  t[0] = f2b(a.x); t[1] = f2b(a.y); t[2] = f2b(a.z); t[3] = f2b(a.w);
  t[4] = f2b(b.x); t[5] = f2b(b.y); t[6] = f2b(b.z); t[7] = f2b(b.w);
  return *(bf16x8*)t;
}

__device__ __forceinline__ bf16x8 cvt8s(const float* src, float sc) {
  float4 a = *(const float4*)(src);
  float4 b = *(const float4*)(src + 4);
  u16 t[8];
  t[0] = f2b(a.x * sc); t[1] = f2b(a.y * sc); t[2] = f2b(a.z * sc); t[3] = f2b(a.w * sc);
  t[4] = f2b(b.x * sc); t[5] = f2b(b.y * sc); t[6] = f2b(b.z * sc); t[7] = f2b(b.w * sc);
  return *(bf16x8*)t;
}

// prep: Kb = bf16(K) same layout [j][h][d]; Vtb = bf16(V) transposed [h][d][j]
__global__ __launch_bounds__(256)
void prep(const float* __restrict__ K, const float* __restrict__ V,
          u16* __restrict__ Kb, u16* __restrict__ Vtb) {
  __shared__ __align__(16) u16 T[64 * 136];
  int b = (int)blockIdx.x;
  int tid = (int)threadIdx.x;
  if (b < 4096) {                       // K: 4096*256*8 = SEQ*NH*HD elems
    size_t i = (size_t)b * 256 + tid;
    bf16x8 v = cvt8(K + i * 8);
    *(uint4*)(Kb + i * 8) = *(uint4*)&v;
  } else {                              // V transpose: 32 heads x 32 j-tiles
    b -= 4096;
    int h = b >> 5, jt = b & 31;
    // stage 64(j) x 128(d) bf16; 16B group g stored at g ^ ((j>>3)&7)
    #pragma unroll
    for (int it = 0; it < 4; ++it) {
      int c = tid + it * 256;           // [0,1024): j = c>>4, grp = c&15
      int j = c >> 4, grp = c & 15;
      bf16x8 v = cvt8(V + ((size_t)(jt * 64 + j) * NH + h) * HD + (grp << 3));
      *(uint4*)(T + j * 136 + ((grp ^ ((j >> 3) & 7)) << 3)) = *(uint4*)&v;
    }
    __syncthreads();
    // each thread emits 2 d-rows x 8 j via 8 paired b32 reads (conflict-free)
    #pragma unroll
    for (int it = 0; it < 2; ++it) {
      int c = tid + it * 256;           // [0,512): d0 = 2*(c>>3), jg = (c&7)*8
      int d0 = (c >> 3) << 1, k = c & 7, jg = k << 3;
      int off = (((d0 >> 3) ^ k) << 3) | (d0 & 7);
      u16 lo[8], hi[8];
      #pragma unroll
      for (int e = 0; e < 8; ++e) {
        unsigned w = *(const unsigned*)(T + (jg + e) * 136 + off);
        lo[e] = (u16)w; hi[e] = (u16)(w >> 16);
      }
      *(uint4*)(Vtb + ((size_t)h * HD + d0) * SEQ + jt * 64 + jg) = *(uint4*)lo;
      *(uint4*)(Vtb + ((size_t)h * HD + d0 + 1) * SEQ + jt * 64 + jg) = *(uint4*)hi;
    }
  }
}

template <bool PRE>
__global__ __launch_bounds__(256)
void attn_roco(const float* __restrict__ Qg, const float* __restrict__ Kg,
               const float* __restrict__ Vg, const u16* __restrict__ Kb,
               const u16* __restrict__ Vtb, float* __restrict__ Og,
               float* __restrict__ RS) {
  // 40 KiB -> 3 blocks/CU (12 waves). T14 reg-prefetch: global->reg loads for
  // tile t+1 issue AFTER barrier (b) and drain at next barrier (a), fully
  // hidden under QK/exp/PV compute; both barriers wait only on LDS writes.
  __shared__ __align__(16) u16 smem[20480];
  u16* Ks = smem;             // 64x128, read addr grp = g ^ (row&15)
  u16* Vt = smem + VT_OFF;    // [d][64j], read addr grp = g ^ vt_key(d)
  u16* Ps = smem + PS_OFF;    // 64x64, phys grp = pg ^ (prow&7)

  const int tid = threadIdx.x;
  const int wv  = tid >> 6;
  const int ln  = tid & 63;
  const int qd  = ln >> 4;
  const int cc  = ln & 15;

  const int h = (int)blockIdx.x & 31;
  // serpentine schedule: per-CU tile-work sums to a constant under RR dispatch
  const int pos = ((int)blockIdx.x >> 5) & 7;
  const int grp = (int)blockIdx.x >> 8;
  int qt;
  if      (grp == 0) qt = 31 - pos;
  else if (grp == 1) qt = 16 + pos;
  else if (grp == 2) qt = 15 - pos;
  else               qt = pos;

  const int qbase  = qt * BQ;
  const int ntiles = qt + 1;

  // ---- Q tile into registers, pre-scaled by beta*log2e ----
  const float qsc = 0.08838834764831845f * 1.4426950408889634f;
  bf16x8 qf[4];
  {
    const float* qp = Qg + ((size_t)(qbase + wv * 16 + cc) * NH + h) * HD;
    #pragma unroll
    for (int kd = 0; kd < 4; ++kd)
      qf[kd] = cvt8s(qp + kd * 32 + qd * 8, qsc);
  }

  const int rbase = wv * 16 + qd * 4;
  float ls[4] = {0.f, 0.f, 0.f, 0.f};

  // ================= PASS A: row sumexp (no max — scores bounded) =========
  if (PRE) {
    const int ntA = (qt >> 1) + 1;           // 128-wide K tiles
    uint4 ka[8];
    auto loadA = [&](int ta) {
      #pragma unroll
      for (int it = 0; it < 8; ++it) {
        int c = tid + it * 256;              // [0,2048): row = c>>4
        int row = c >> 4, g = (c & 15) ^ (row & 15);
        ka[it] = *(const uint4*)(Kb + ((size_t)(ta * 128 + row) * NH + h) * HD +
                                 (g << 3));
      }
    };
    loadA(0);
    for (int ta = 0; ta < ntA; ++ta) {
      __syncthreads();                       // (a) prev compute done; regs ready
      #pragma unroll
      for (int it = 0; it < 8; ++it)
        *(uint4*)(smem + (size_t)(tid + it * 256) * 8) = ka[it];
      __syncthreads();                       // (b) LDS visible
      if (ta + 1 < ntA) loadA(ta + 1);       // prefetch, hidden under compute

      const bool last = (ta == ntA - 1);
      // even qt: last tile's upper 64 cols fully masked for all waves
      const bool skipHi = last && !(qt & 1);
      f32x4 S[8];
      #pragma unroll
      for (int f = 0; f < 8; ++f)
        #pragma unroll
        for (int r = 0; r < 4; ++r) S[f][r] = 0.f;

      #pragma unroll
      for (int kd = 0; kd < 4; ++kd) {
        #pragma unroll
        for (int f = 0; f < 8; ++f) {
          if (!(skipHi && f >= 4)) {
            bf16x8 b = *(const bf16x8*)(smem + (f * 16 + cc) * 128 +
                                        (((kd * 4 + qd) ^ cc) << 3));
            S[f] = __builtin_amdgcn_mfma_f32_16x16x32_bf16(qf[kd], b, S[f], 0, 0, 0);
          }
        }
      }

      #pragma unroll
      for (int r = 0; r < 4; ++r) {
        const int ig = qbase + rbase + r;
        float acc = 0.f;
        #pragma unroll
        for (int f = 0; f < 8; ++f) {
          float e = __builtin_amdgcn_exp2f(S[f][r]);
          if (last && (ta * 128 + f * 16 + cc) > ig) e = 0.f;
          acc += e;
        }
        ls[r] += acc;
      }
    }
  } else {
    for (int t = 0; t < ntiles; ++t) {
      __syncthreads();
      #pragma unroll
      for (int it = 0; it < 4; ++it) {
        int c = tid + it * 256;
        int row = c >> 4, g = c & 15;
        bf16x8 kv = cvt8(Kg + ((size_t)(t * BK + row) * NH + h) * HD + (g << 3));
        *(uint4*)(Ks + row * 128 + ((g ^ (row & 15)) << 3)) = *(uint4*)&kv;
      }
      __syncthreads();

      f32x4 S[4];
      #pragma unroll
      for (int f = 0; f < 4; ++f)
        #pragma unroll
        for (int r = 0; r < 4; ++r) S[f][r] = 0.f;

      #pragma unroll
      for (int kd = 0; kd < 4; ++kd) {
        #pragma unroll
        for (int f = 0; f < 4; ++f) {
          bf16x8 b = *(const bf16x8*)(Ks + (f * 16 + cc) * 128 +
                                      (((kd * 4 + qd) ^ cc) << 3));
          S[f] = __builtin_amdgcn_mfma_f32_16x16x32_bf16(qf[kd], b, S[f], 0, 0, 0);
        }
      }

      const bool diag = (t == qt);
      #pragma unroll
      for (int r = 0; r < 4; ++r) {
        const int iloc = rbase + r;
        float acc = 0.f;
        #pragma unroll
        for (int f = 0; f < 4; ++f) {
          float e = __builtin_amdgcn_exp2f(S[f][r]);
          if (diag && (f * 16 + cc) > iloc) e = 0.f;
          acc += e;
        }
        ls[r] += acc;
      }
    }
  }

  // ---- one-shot row reduce ----
  float invl[4];
  #pragma unroll
  for (int r = 0; r < 4; ++r) {
    #pragma unroll
    for (int off = 1; off < 16; off <<= 1)
      ls[r] += __shfl_xor(ls[r], off);
    invl[r] = 1.f / ls[r];
  }

  f32x4 O[8];
  #pragma unroll
  for (int f = 0; f < 8; ++f)
    #pragma unroll
    for (int r = 0; r < 4; ++r) O[f][r] = 0.f;

  float* ws_s = RS + (size_t)h * SEQ;
  float* ws_q = RS + (size_t)NH * SEQ + (size_t)h * SEQ;

  // ================= PASS B: exact P, O += P*V, column sums =================
  uint4 kr[4], vr[4];
  auto loadB = [&](int t) {
    #pragma unroll
    for (int it = 0; it < 4; ++it) {
      int c = tid + it * 256;                // K tile 64x128
      int row = c >> 4, g = (c & 15) ^ (row & 15);
      kr[it] = *(const uint4*)(Kb + ((size_t)(t * BK + row) * NH + h) * HD +
                               (g << 3));
    }
    #pragma unroll
    for (int it = 0; it < 4; ++it) {
      int c = tid + it * 256;                // V tile [d][64j]
      int d = c >> 3, g = (c & 7) ^ vt_key(d);
      vr[it] = *(const uint4*)(Vtb + ((size_t)h * HD + d) * SEQ + t * BK +
                               (g << 3));
    }
  };

  if (PRE) loadB(0);
  for (int t = 0; t < ntiles; ++t) {
    __syncthreads();                         // (a) prev compute done; regs ready
    if (PRE) {
      #pragma unroll
      for (int it = 0; it < 4; ++it)
        *(uint4*)(Ks + (size_t)(tid + it * 256) * 8) = kr[it];
      #pragma unroll
      for (int it = 0; it < 4; ++it)
        *(uint4*)(Vt + (size_t)(tid + it * 256) * 8) = vr[it];
      __syncthreads();                       // (b) LDS visible
      if (t + 1 < ntiles) loadB(t + 1);      // prefetch, hidden under compute
    } else {
      #pragma unroll
      for (int it = 0; it < 4; ++it) {
        int c = tid + it * 256;
        int row = c >> 4, g = c & 15;
        bf16x8 kv = cvt8(Kg + ((size_t)(t * BK + row) * NH + h) * HD + (g << 3));
        *(uint4*)(Ks + row * 128 + ((g ^ (row & 15)) << 3)) = *(uint4*)&kv;
      }
      #pragma unroll
      for (int it = 0; it < 4; ++it) {
        int c = tid + it * 256;
        int j = c >> 4, d0 = (c & 15) << 3;
        bf16x8 v = cvt8(Vg + ((size_t)(t * BK + j) * NH + h) * HD + d0);
        u16 ev[8];
        *(uint4*)ev = *(uint4*)&v;
        #pragma unroll
        for (int e = 0; e < 8; ++e) {
          int d = d0 + e;
          Vt[d * BK + ((((j >> 3) ^ vt_key(d)) << 3)) + (j & 7)] = ev[e];
        }
      }
      __syncthreads();                       // staging visible
    }

    f32x4 S[4];
    #pragma unroll
    for (int f = 0; f < 4; ++f)
      #pragma unroll
      for (int r = 0; r < 4; ++r) S[f][r] = 0.f;

    #pragma unroll
    for (int kd = 0; kd < 4; ++kd) {
      #pragma unroll
      for (int f = 0; f < 4; ++f) {
        bf16x8 b = *(const bf16x8*)(Ks + (f * 16 + cc) * 128 +
                                    (((kd * 4 + qd) ^ cc) << 3));
        S[f] = __builtin_amdgcn_mfma_f32_16x16x32_bf16(qf[kd], b, S[f], 0, 0, 0);
      }
    }

    const bool diag = (t == qt);
    float cs[4] = {0.f, 0.f, 0.f, 0.f}, cq[4] = {0.f, 0.f, 0.f, 0.f};
    #pragma unroll
    for (int r = 0; r < 4; ++r) {
      const int iloc = rbase + r;
      const int prow = wv * 16 + qd * 4 + r;
      #pragma unroll
      for (int f = 0; f < 4; ++f) {
        float p = __builtin_amdgcn_exp2f(S[f][r]) * invl[r];
        if (diag && (f * 16 + cc) > iloc) p = 0.f;
        cs[f] += p;
        cq[f] += p * p;
        int pg = f * 2 + (cc >> 3);
        Ps[prow * 64 + ((pg ^ (prow & 7)) << 3) + (cc & 7)] = f2b(p);
      }
    }
    // column sums: combine quads, one atomic per column per wave
    #pragma unroll
    for (int f = 0; f < 4; ++f) {
      cs[f] += __shfl_xor(cs[f], 16); cs[f] += __shfl_xor(cs[f], 32);
      cq[f] += __shfl_xor(cq[f], 16); cq[f] += __shfl_xor(cq[f], 32);
      if (qd == f) {
        int j = t * BK + f * 16 + cc;
        atomicAdd(ws_s + j, cs[f]);
        atomicAdd(ws_q + j, cq[f]);
      }
    }
    // PV: O[16 x 128] += P[16 x 64] * V[64 x 128]
    #pragma unroll
    for (int ks2 = 0; ks2 < 2; ++ks2) {
      bf16x8 a = *(const bf16x8*)(Ps + (wv * 16 + cc) * 64 +
                                  (((ks2 * 4 + qd) ^ (cc & 7)) << 3));
      #pragma unroll
      for (int f2 = 0; f2 < 8; ++f2) {
        int d = f2 * 16 + cc;
        int jb = ks2 * 4 + qd;
        bf16x8 b = *(const bf16x8*)(Vt + d * BK + ((jb ^ vt_key(d)) << 3));
        O[f2] = __builtin_amdgcn_mfma_f32_16x16x32_bf16(a, b, O[f2], 0, 0, 0);
      }
    }
  }

  // ---- epilogue: O already normalized (invl folded into P) ----
  #pragma unroll
  for (int f2 = 0; f2 < 8; ++f2) {
    #pragma unroll
    for (int r = 0; r < 4; ++r) {
      int i = qbase + rbase + r;
      int d = f2 * 16 + cc;
      Og[((size_t)i * NH + h) * HD + d] = O[f2][r];
    }
  }
}

extern "C" void kernel_launch(void* const* d_in, const int* in_sizes, int n_in,
                              void* d_out, int out_size, void* d_ws, size_t ws_size,
                              hipStream_t stream) {
  (void)in_sizes; (void)n_in; (void)out_size;
  const float* Qg = (const float*)d_in[0];
  const float* Kg = (const float*)d_in[1];
  const float* Vg = (const float*)d_in[2];
  float* Og = (float*)d_out;

  const size_t roco_elems = (size_t)2 * NH * SEQ;
  const size_t tens = (size_t)SEQ * NH * HD;
  const size_t need = 2 * tens * 2;         // Kb + Vtb (bf16)
  const bool pre = ws_size >= need;

  // roco accumulators live directly in the output buffer
  float* RS = Og + tens;
  (void)hipMemsetAsync(RS, 0, roco_elems * sizeof(float), stream);

  u16* Kb  = (u16*)d_ws;
  u16* Vtb = Kb + tens;

  if (pre) {
    prep<<<dim3(4096 + 1024), dim3(256), 0, stream>>>(Kg, Vg, Kb, Vtb);
    attn_roco<true><<<dim3(NH * (SEQ / BQ)), dim3(256), 0, stream>>>(
        Qg, Kg, Vg, Kb, Vtb, Og, RS);
  } else {
    attn_roco<false><<<dim3(NH * (SEQ / BQ)), dim3(256), 0, stream>>>(
        Qg, Kg, Vg, Kb, Vtb, Og, RS);
  }
}

// Round 5
// 232.396 us; speedup vs baseline: 1.8975x; 1.8975x over previous
//
#include <hip/hip_runtime.h>
#include <hip/hip_bf16.h>

typedef unsigned short u16;
typedef __attribute__((ext_vector_type(8))) short bf16x8;  // 8 bf16 = 4 VGPRs
typedef __attribute__((ext_vector_type(4))) float f32x4;

#define NH   32
#define HD   128
#define SEQ  2048
#define BQ   64
#define BK   64

// smem (u16 units): Ks [0,8192) Vt [8192,16384) Ps [16384,20480)  = 40960 B
// pass A overlays KsA (128x128) on [0,16384)
#define VT_OFF 8192
#define PS_OFF 16384

// Vt swizzle key: phys group p = g ^ vt_key(d) within a d-row of 8 groups
__device__ __forceinline__ int vt_key(int d) { return (d & 7) ^ ((d >> 3) & 7); }

__device__ __forceinline__ u16 f2b(float x) {
  __hip_bfloat16 hb = __float2bfloat16(x);
  return *(u16*)&hb;
}

// load 8 fp32 (32B), convert to bf16x8
__device__ __forceinline__ bf16x8 cvt8(const float* src) {
  float4 a = *(const float4*)(src);
  float4 b = *(const float4*)(src + 4);
  u16 t[8];
  t[0] = f2b(a.x); t[1] = f2b(a.y); t[2] = f2b(a.z); t[3] = f2b(a.w);
  t[4] = f2b(b.x); t[5] = f2b(b.y); t[6] = f2b(b.z); t[7] = f2b(b.w);
  return *(bf16x8*)t;
}

__device__ __forceinline__ bf16x8 cvt8s(const float* src, float sc) {
  float4 a = *(const float4*)(src);
  float4 b = *(const float4*)(src + 4);
  u16 t[8];
  t[0] = f2b(a.x * sc); t[1] = f2b(a.y * sc); t[2] = f2b(a.z * sc); t[3] = f2b(a.w * sc);
  t[4] = f2b(b.x * sc); t[5] = f2b(b.y * sc); t[6] = f2b(b.z * sc); t[7] = f2b(b.w * sc);
  return *(bf16x8*)t;
}

// prep: Kb = bf16(K) same layout [j][h][d]; Vtb = bf16(V) transposed [h][d][j]
__global__ __launch_bounds__(256)
void prep(const float* __restrict__ K, const float* __restrict__ V,
          u16* __restrict__ Kb, u16* __restrict__ Vtb) {
  __shared__ __align__(16) u16 T[64 * 136];
  int b = (int)blockIdx.x;
  int tid = (int)threadIdx.x;
  if (b < 4096) {                       // K: 4096*256*8 = SEQ*NH*HD elems
    size_t i = (size_t)b * 256 + tid;
    bf16x8 v = cvt8(K + i * 8);
    *(uint4*)(Kb + i * 8) = *(uint4*)&v;
  } else {                              // V transpose: 32 heads x 32 j-tiles
    b -= 4096;
    int h = b >> 5, jt = b & 31;
    // stage 64(j) x 128(d) bf16; 16B group g stored at g ^ ((j>>3)&7)
    #pragma unroll
    for (int it = 0; it < 4; ++it) {
      int c = tid + it * 256;           // [0,1024): j = c>>4, grp = c&15
      int j = c >> 4, grp = c & 15;
      bf16x8 v = cvt8(V + ((size_t)(jt * 64 + j) * NH + h) * HD + (grp << 3));
      *(uint4*)(T + j * 136 + ((grp ^ ((j >> 3) & 7)) << 3)) = *(uint4*)&v;
    }
    __syncthreads();
    // each thread emits 2 d-rows x 8 j via 8 paired b32 reads (conflict-free)
    #pragma unroll
    for (int it = 0; it < 2; ++it) {
      int c = tid + it * 256;           // [0,512): d0 = 2*(c>>3), jg = (c&7)*8
      int d0 = (c >> 3) << 1, k = c & 7, jg = k << 3;
      int off = (((d0 >> 3) ^ k) << 3) | (d0 & 7);
      u16 lo[8], hi[8];
      #pragma unroll
      for (int e = 0; e < 8; ++e) {
        unsigned w = *(const unsigned*)(T + (jg + e) * 136 + off);
        lo[e] = (u16)w; hi[e] = (u16)(w >> 16);
      }
      *(uint4*)(Vtb + ((size_t)h * HD + d0) * SEQ + jt * 64 + jg) = *(uint4*)lo;
      *(uint4*)(Vtb + ((size_t)h * HD + d0 + 1) * SEQ + jt * 64 + jg) = *(uint4*)hi;
    }
  }
}

// per-lane source base for a K-tile row: c in [0,2048) -> row=c>>4, logical
// group g = (c&15)^(row&15) (so LDS position c holds phys-swizzled layout)
#define KSRC(it) (Kb + ((size_t)((tid + (it)*256) >> 4) * NH + h) * HD + \
                  (((((tid + (it)*256) & 15) ^ (((tid + (it)*256) >> 4) & 15))) << 3))
#define VSRC(it) (Vtb + ((size_t)h * HD + ((tid + (it)*256) >> 3)) * SEQ + \
                  (((((tid + (it)*256) & 7) ^ vt_key((tid + (it)*256) >> 3))) << 3))

template <bool PRE>
__global__ __launch_bounds__(256, 2)
void attn_roco(const float* __restrict__ Qg, const float* __restrict__ Kg,
               const float* __restrict__ Vg, const u16* __restrict__ Kb,
               const u16* __restrict__ Vtb, float* __restrict__ Og,
               float* __restrict__ RS) {
  // 40 KiB -> 3 blocks/CU (12 waves). T14 reg-prefetch with NAMED uint4 regs
  // (no arrays/lambdas -> no scratch): tile t+1 global->reg loads issue after
  // barrier (b), hidden under tile t compute, regs->LDS between barriers.
  __shared__ __align__(16) u16 smem[20480];
  u16* Ks = smem;             // 64x128, read addr grp = g ^ (row&15)
  u16* Vt = smem + VT_OFF;    // [d][64j], read addr grp = g ^ vt_key(d)
  u16* Ps = smem + PS_OFF;    // 64x64, phys grp = pg ^ (prow&7)

  const int tid = threadIdx.x;
  const int wv  = tid >> 6;
  const int ln  = tid & 63;
  const int qd  = ln >> 4;
  const int cc  = ln & 15;

  const int h = (int)blockIdx.x & 31;
  // serpentine schedule: per-CU tile-work sums to a constant under RR dispatch
  const int pos = ((int)blockIdx.x >> 5) & 7;
  const int grp = (int)blockIdx.x >> 8;
  int qt;
  if      (grp == 0) qt = 31 - pos;
  else if (grp == 1) qt = 16 + pos;
  else if (grp == 2) qt = 15 - pos;
  else               qt = pos;

  const int qbase  = qt * BQ;
  const int ntiles = qt + 1;

  // ---- Q tile into registers, pre-scaled by beta*log2e ----
  const float qsc = 0.08838834764831845f * 1.4426950408889634f;
  bf16x8 qf[4];
  {
    const float* qp = Qg + ((size_t)(qbase + wv * 16 + cc) * NH + h) * HD;
    #pragma unroll
    for (int kd = 0; kd < 4; ++kd)
      qf[kd] = cvt8s(qp + kd * 32 + qd * 8, qsc);
  }

  const int rbase = wv * 16 + qd * 4;
  float ls[4] = {0.f, 0.f, 0.f, 0.f};

  // ================= PASS A: row sumexp (no max — scores bounded) =========
  if (PRE) {
    const int ntA = (qt >> 1) + 1;           // 128-wide K tiles
    const size_t strA = (size_t)128 * NH * HD;
    const u16 *pa0 = KSRC(0), *pa1 = KSRC(1), *pa2 = KSRC(2), *pa3 = KSRC(3),
              *pa4 = KSRC(4), *pa5 = KSRC(5), *pa6 = KSRC(6), *pa7 = KSRC(7);
    uint4 a0 = *(const uint4*)pa0, a1 = *(const uint4*)pa1,
          a2 = *(const uint4*)pa2, a3 = *(const uint4*)pa3,
          a4 = *(const uint4*)pa4, a5 = *(const uint4*)pa5,
          a6 = *(const uint4*)pa6, a7 = *(const uint4*)pa7;
    for (int ta = 0; ta < ntA; ++ta) {
      __syncthreads();                       // (a) prev compute done; regs ready
      *(uint4*)(smem + ((size_t)tid + 0 * 256) * 8) = a0;
      *(uint4*)(smem + ((size_t)tid + 1 * 256) * 8) = a1;
      *(uint4*)(smem + ((size_t)tid + 2 * 256) * 8) = a2;
      *(uint4*)(smem + ((size_t)tid + 3 * 256) * 8) = a3;
      *(uint4*)(smem + ((size_t)tid + 4 * 256) * 8) = a4;
      *(uint4*)(smem + ((size_t)tid + 5 * 256) * 8) = a5;
      *(uint4*)(smem + ((size_t)tid + 6 * 256) * 8) = a6;
      *(uint4*)(smem + ((size_t)tid + 7 * 256) * 8) = a7;
      __syncthreads();                       // (b) LDS visible
      if (ta + 1 < ntA) {                    // prefetch, hidden under compute
        const size_t o = (size_t)(ta + 1) * strA;
        a0 = *(const uint4*)(pa0 + o); a1 = *(const uint4*)(pa1 + o);
        a2 = *(const uint4*)(pa2 + o); a3 = *(const uint4*)(pa3 + o);
        a4 = *(const uint4*)(pa4 + o); a5 = *(const uint4*)(pa5 + o);
        a6 = *(const uint4*)(pa6 + o); a7 = *(const uint4*)(pa7 + o);
      }

      const bool last = (ta == ntA - 1);
      // even qt: last tile's upper 64 cols fully masked for all waves
      const bool skipHi = last && !(qt & 1);
      f32x4 S[8];
      #pragma unroll
      for (int f = 0; f < 8; ++f)
        #pragma unroll
        for (int r = 0; r < 4; ++r) S[f][r] = 0.f;

      #pragma unroll
      for (int kd = 0; kd < 4; ++kd) {
        #pragma unroll
        for (int f = 0; f < 8; ++f) {
          if (!(skipHi && f >= 4)) {
            bf16x8 b = *(const bf16x8*)(smem + (f * 16 + cc) * 128 +
                                        (((kd * 4 + qd) ^ cc) << 3));
            S[f] = __builtin_amdgcn_mfma_f32_16x16x32_bf16(qf[kd], b, S[f], 0, 0, 0);
          }
        }
      }

      #pragma unroll
      for (int r = 0; r < 4; ++r) {
        const int ig = qbase + rbase + r;
        float acc = 0.f;
        #pragma unroll
        for (int f = 0; f < 8; ++f) {
          float e = __builtin_amdgcn_exp2f(S[f][r]);
          if (last && (ta * 128 + f * 16 + cc) > ig) e = 0.f;
          acc += e;
        }
        ls[r] += acc;
      }
    }
  } else {
    for (int t = 0; t < ntiles; ++t) {
      __syncthreads();
      #pragma unroll
      for (int it = 0; it < 4; ++it) {
        int c = tid + it * 256;
        int row = c >> 4, g = c & 15;
        bf16x8 kv = cvt8(Kg + ((size_t)(t * BK + row) * NH + h) * HD + (g << 3));
        *(uint4*)(Ks + row * 128 + ((g ^ (row & 15)) << 3)) = *(uint4*)&kv;
      }
      __syncthreads();

      f32x4 S[4];
      #pragma unroll
      for (int f = 0; f < 4; ++f)
        #pragma unroll
        for (int r = 0; r < 4; ++r) S[f][r] = 0.f;

      #pragma unroll
      for (int kd = 0; kd < 4; ++kd) {
        #pragma unroll
        for (int f = 0; f < 4; ++f) {
          bf16x8 b = *(const bf16x8*)(Ks + (f * 16 + cc) * 128 +
                                      (((kd * 4 + qd) ^ cc) << 3));
          S[f] = __builtin_amdgcn_mfma_f32_16x16x32_bf16(qf[kd], b, S[f], 0, 0, 0);
        }
      }

      const bool diag = (t == qt);
      #pragma unroll
      for (int r = 0; r < 4; ++r) {
        const int iloc = rbase + r;
        float acc = 0.f;
        #pragma unroll
        for (int f = 0; f < 4; ++f) {
          float e = __builtin_amdgcn_exp2f(S[f][r]);
          if (diag && (f * 16 + cc) > iloc) e = 0.f;
          acc += e;
        }
        ls[r] += acc;
      }
    }
  }

  // ---- one-shot row reduce ----
  float invl[4];
  #pragma unroll
  for (int r = 0; r < 4; ++r) {
    #pragma unroll
    for (int off = 1; off < 16; off <<= 1)
      ls[r] += __shfl_xor(ls[r], off);
    invl[r] = 1.f / ls[r];
  }

  f32x4 O[8];
  #pragma unroll
  for (int f = 0; f < 8; ++f)
    #pragma unroll
    for (int r = 0; r < 4; ++r) O[f][r] = 0.f;

  float* ws_s = RS + (size_t)h * SEQ;
  float* ws_q = RS + (size_t)NH * SEQ + (size_t)h * SEQ;

  // ================= PASS B: exact P, O += P*V, column sums =================
  const size_t strK = (size_t)BK * NH * HD;   // K advance per tile (elems)
  const u16 *pk0 = KSRC(0), *pk1 = KSRC(1), *pk2 = KSRC(2), *pk3 = KSRC(3);
  const u16 *pv0 = VSRC(0), *pv1 = VSRC(1), *pv2 = VSRC(2), *pv3 = VSRC(3);
  uint4 k0, k1, k2, k3, v0, v1, v2, v3;
  if (PRE) {
    k0 = *(const uint4*)pk0; k1 = *(const uint4*)pk1;
    k2 = *(const uint4*)pk2; k3 = *(const uint4*)pk3;
    v0 = *(const uint4*)pv0; v1 = *(const uint4*)pv1;
    v2 = *(const uint4*)pv2; v3 = *(const uint4*)pv3;
  }
  for (int t = 0; t < ntiles; ++t) {
    __syncthreads();                         // (a) prev compute done; regs ready
    if (PRE) {
      *(uint4*)(Ks + ((size_t)tid + 0 * 256) * 8) = k0;
      *(uint4*)(Ks + ((size_t)tid + 1 * 256) * 8) = k1;
      *(uint4*)(Ks + ((size_t)tid + 2 * 256) * 8) = k2;
      *(uint4*)(Ks + ((size_t)tid + 3 * 256) * 8) = k3;
      *(uint4*)(Vt + ((size_t)tid + 0 * 256) * 8) = v0;
      *(uint4*)(Vt + ((size_t)tid + 1 * 256) * 8) = v1;
      *(uint4*)(Vt + ((size_t)tid + 2 * 256) * 8) = v2;
      *(uint4*)(Vt + ((size_t)tid + 3 * 256) * 8) = v3;
      __syncthreads();                       // (b) LDS visible
      if (t + 1 < ntiles) {                  // prefetch, hidden under compute
        const size_t ok = (size_t)(t + 1) * strK;
        const size_t ov = (size_t)(t + 1) * BK;
        k0 = *(const uint4*)(pk0 + ok); k1 = *(const uint4*)(pk1 + ok);
        k2 = *(const uint4*)(pk2 + ok); k3 = *(const uint4*)(pk3 + ok);
        v0 = *(const uint4*)(pv0 + ov); v1 = *(const uint4*)(pv1 + ov);
        v2 = *(const uint4*)(pv2 + ov); v3 = *(const uint4*)(pv3 + ov);
      }
    } else {
      #pragma unroll
      for (int it = 0; it < 4; ++it) {
        int c = tid + it * 256;
        int row = c >> 4, g = c & 15;
        bf16x8 kv = cvt8(Kg + ((size_t)(t * BK + row) * NH + h) * HD + (g << 3));
        *(uint4*)(Ks + row * 128 + ((g ^ (row & 15)) << 3)) = *(uint4*)&kv;
      }
      #pragma unroll
      for (int it = 0; it < 4; ++it) {
        int c = tid + it * 256;
        int j = c >> 4, d0 = (c & 15) << 3;
        bf16x8 v = cvt8(Vg + ((size_t)(t * BK + j) * NH + h) * HD + d0);
        u16 ev[8];
        *(uint4*)ev = *(uint4*)&v;
        #pragma unroll
        for (int e = 0; e < 8; ++e) {
          int d = d0 + e;
          Vt[d * BK + ((((j >> 3) ^ vt_key(d)) << 3)) + (j & 7)] = ev[e];
        }
      }
      __syncthreads();                       // staging visible
    }

    f32x4 S[4];
    #pragma unroll
    for (int f = 0; f < 4; ++f)
      #pragma unroll
      for (int r = 0; r < 4; ++r) S[f][r] = 0.f;

    #pragma unroll
    for (int kd = 0; kd < 4; ++kd) {
      #pragma unroll
      for (int f = 0; f < 4; ++f) {
        bf16x8 b = *(const bf16x8*)(Ks + (f * 16 + cc) * 128 +
                                    (((kd * 4 + qd) ^ cc) << 3));
        S[f] = __builtin_amdgcn_mfma_f32_16x16x32_bf16(qf[kd], b, S[f], 0, 0, 0);
      }
    }

    const bool diag = (t == qt);
    float cs[4] = {0.f, 0.f, 0.f, 0.f}, cq[4] = {0.f, 0.f, 0.f, 0.f};
    #pragma unroll
    for (int r = 0; r < 4; ++r) {
      const int iloc = rbase + r;
      const int prow = wv * 16 + qd * 4 + r;
      #pragma unroll
      for (int f = 0; f < 4; ++f) {
        float p = __builtin_amdgcn_exp2f(S[f][r]) * invl[r];
        if (diag && (f * 16 + cc) > iloc) p = 0.f;
        cs[f] += p;
        cq[f] += p * p;
        int pg = f * 2 + (cc >> 3);
        Ps[prow * 64 + ((pg ^ (prow & 7)) << 3) + (cc & 7)] = f2b(p);
      }
    }
    // column sums: combine quads, one atomic per column per wave
    #pragma unroll
    for (int f = 0; f < 4; ++f) {
      cs[f] += __shfl_xor(cs[f], 16); cs[f] += __shfl_xor(cs[f], 32);
      cq[f] += __shfl_xor(cq[f], 16); cq[f] += __shfl_xor(cq[f], 32);
      if (qd == f) {
        int j = t * BK + f * 16 + cc;
        atomicAdd(ws_s + j, cs[f]);
        atomicAdd(ws_q + j, cq[f]);
      }
    }
    // PV: O[16 x 128] += P[16 x 64] * V[64 x 128]
    #pragma unroll
    for (int ks2 = 0; ks2 < 2; ++ks2) {
      bf16x8 a = *(const bf16x8*)(Ps + (wv * 16 + cc) * 64 +
                                  (((ks2 * 4 + qd) ^ (cc & 7)) << 3));
      #pragma unroll
      for (int f2 = 0; f2 < 8; ++f2) {
        int d = f2 * 16 + cc;
        int jb = ks2 * 4 + qd;
        bf16x8 b = *(const bf16x8*)(Vt + d * BK + ((jb ^ vt_key(d)) << 3));
        O[f2] = __builtin_amdgcn_mfma_f32_16x16x32_bf16(a, b, O[f2], 0, 0, 0);
      }
    }
  }

  // ---- epilogue: O already normalized (invl folded into P) ----
  #pragma unroll
  for (int f2 = 0; f2 < 8; ++f2) {
    #pragma unroll
    for (int r = 0; r < 4; ++r) {
      int i = qbase + rbase + r;
      int d = f2 * 16 + cc;
      Og[((size_t)i * NH + h) * HD + d] = O[f2][r];
    }
  }
}

extern "C" void kernel_launch(void* const* d_in, const int* in_sizes, int n_in,
                              void* d_out, int out_size, void* d_ws, size_t ws_size,
                              hipStream_t stream) {
  (void)in_sizes; (void)n_in; (void)out_size;
  const float* Qg = (const float*)d_in[0];
  const float* Kg = (const float*)d_in[1];
  const float* Vg = (const float*)d_in[2];
  float* Og = (float*)d_out;

  const size_t roco_elems = (size_t)2 * NH * SEQ;
  const size_t tens = (size_t)SEQ * NH * HD;
  const size_t need = 2 * tens * 2;         // Kb + Vtb (bf16)
  const bool pre = ws_size >= need;

  // roco accumulators live directly in the output buffer
  float* RS = Og + tens;
  (void)hipMemsetAsync(RS, 0, roco_elems * sizeof(float), stream);

  u16* Kb  = (u16*)d_ws;
  u16* Vtb = Kb + tens;

  if (pre) {
    prep<<<dim3(4096 + 1024), dim3(256), 0, stream>>>(Kg, Vg, Kb, Vtb);
    attn_roco<true><<<dim3(NH * (SEQ / BQ)), dim3(256), 0, stream>>>(
        Qg, Kg, Vg, Kb, Vtb, Og, RS);
  } else {
    attn_roco<false><<<dim3(NH * (SEQ / BQ)), dim3(256), 0, stream>>>(
        Qg, Kg, Vg, Kb, Vtb, Og, RS);
  }
}